// Round 1
// baseline (8140.641 us; speedup 1.0000x reference)
//
#include <hip/hip_runtime.h>

// Fused 3x(3x3 conv) + ReLU, B=4, C 3->16->16->16, H=W=1536, SAME pad.
// Strategy: one block per 32x32 output tile (per batch image). Stage x tile
// with halo 3 into LDS (bf16), compute h1 (36x36x16) into LDS (bf16),
// h2 (34x34x16) into LDS (bf16, reusing the x region), then conv3+ReLU
// direct to global. fp32 accumulation throughout; bf16 only for LDS storage
// (threshold is 2% of absmax ~= 0.3725, bf16 staging error is ~100x below).
// Weights are read with wave-uniform addresses -> scalar s_load (K$), keeping
// the VALU free for FMAs.

#define HH 1536
#define WW 1536
#define BB 4
#define TS 32        // output tile edge
#define NT (HH / TS) // 48 tiles per edge

__device__ __forceinline__ float b2f(unsigned short h) {
    union { unsigned u; float f; } v; v.u = ((unsigned)h) << 16; return v.f;
}
__device__ __forceinline__ unsigned short f2b(float f) {
    union { float f; unsigned u; } v; v.f = f;
    unsigned r = v.u + 0x7FFFu + ((v.u >> 16) & 1u); // round-to-nearest-even
    return (unsigned short)(r >> 16);
}

extern "C" __global__ __launch_bounds__(512, 2)
void fused_conv3(const float* __restrict__ x,
                 const float* __restrict__ w1,
                 const float* __restrict__ w2,
                 const float* __restrict__ w3,
                 float* __restrict__ out)
{
    // LDS: h1 buffer [16][36][36] bf16 = 41472 B
    //      union buffer: x tile [3][38][38] (4332 elem) / h2 [16][34][34] (18496 elem) = 36992 B
    __shared__ unsigned short sh1[16 * 36 * 36];
    __shared__ unsigned short sxh2[16 * 34 * 34];

    const int tid = threadIdx.x;
    const int blk = blockIdx.x;
    const int b   = blk / (NT * NT);
    const int rr_ = blk % (NT * NT);
    const int ty  = rr_ / NT, tx = rr_ % NT;
    const int y0  = ty * TS, x0 = tx * TS;

    // ---- phase 0: stage x tile (3 x 38 x 38), halo 3, zero-padded ----
    {
        const float* xb = x + (size_t)b * 3 * HH * WW;
        for (int i = tid; i < 3 * 38 * 38; i += 512) {
            int c  = i / (38 * 38);
            int r2 = i - c * (38 * 38);
            int yy = r2 / 38, xx = r2 - yy * 38;
            int gy = y0 - 3 + yy, gx = x0 - 3 + xx;
            float v = 0.f;
            if ((unsigned)gy < (unsigned)HH && (unsigned)gx < (unsigned)WW)
                v = xb[(size_t)c * HH * WW + (size_t)gy * WW + gx];
            sxh2[i] = f2b(v);
        }
    }
    __syncthreads();

    // ---- phase 1: conv1 (3->16) at 36x36 positions (halo 2) ----
    for (int p = tid; p < 36 * 36; p += 512) {
        int yy = p / 36, xx = p - yy * 36;
        int gy = y0 - 2 + yy, gx = x0 - 2 + xx;
        float acc[16];
#pragma unroll
        for (int co = 0; co < 16; ++co) acc[co] = 0.f;
        if ((unsigned)gy < (unsigned)HH && (unsigned)gx < (unsigned)WW) {
            float v[27];
#pragma unroll
            for (int ci = 0; ci < 3; ++ci)
#pragma unroll
                for (int dy = 0; dy < 3; ++dy)
#pragma unroll
                    for (int dx = 0; dx < 3; ++dx)
                        v[ci * 9 + dy * 3 + dx] =
                            b2f(sxh2[(ci * 38 + yy + dy) * 38 + xx + dx]);
#pragma unroll
            for (int co = 0; co < 16; ++co) {
                float a = 0.f;
#pragma unroll
                for (int k = 0; k < 27; ++k)
                    a += w1[co * 27 + k] * v[k];  // w1: uniform -> s_load
                acc[co] = a;
            }
        }
#pragma unroll
        for (int co = 0; co < 16; ++co)
            sh1[(co * 36 + yy) * 36 + xx] = f2b(acc[co]);
    }
    __syncthreads();

    // ---- phase 2: conv2 (16->16) at 34x34 positions (halo 1), into sxh2 ----
    for (int p = tid; p < 34 * 34; p += 512) {
        int yy = p / 34, xx = p - yy * 34;
        int gy = y0 - 1 + yy, gx = x0 - 1 + xx;
        float acc[16];
#pragma unroll
        for (int co = 0; co < 16; ++co) acc[co] = 0.f;
        if ((unsigned)gy < (unsigned)HH && (unsigned)gx < (unsigned)WW) {
#pragma unroll
            for (int ci = 0; ci < 16; ++ci) {
                float v[9];
#pragma unroll
                for (int dy = 0; dy < 3; ++dy)
#pragma unroll
                    for (int dx = 0; dx < 3; ++dx)
                        v[dy * 3 + dx] =
                            b2f(sh1[(ci * 36 + yy + dy) * 36 + xx + dx]);
#pragma unroll
                for (int co = 0; co < 16; ++co) {
#pragma unroll
                    for (int k = 0; k < 9; ++k)
                        acc[co] += w2[(co * 16 + ci) * 9 + k] * v[k];
                }
            }
        }
#pragma unroll
        for (int co = 0; co < 16; ++co)
            sxh2[(co * 34 + yy) * 34 + xx] = f2b(acc[co]);
    }
    __syncthreads();

    // ---- phase 3: conv3 (16->16) + ReLU at 32x32, write global ----
    for (int p = tid; p < 32 * 32; p += 512) {
        int oy = p >> 5, ox = p & 31;
        float acc[16];
#pragma unroll
        for (int co = 0; co < 16; ++co) acc[co] = 0.f;
#pragma unroll
        for (int ci = 0; ci < 16; ++ci) {
            float v[9];
#pragma unroll
            for (int dy = 0; dy < 3; ++dy)
#pragma unroll
                for (int dx = 0; dx < 3; ++dx)
                    v[dy * 3 + dx] =
                        b2f(sxh2[(ci * 34 + oy + dy) * 34 + ox + dx]);
#pragma unroll
            for (int co = 0; co < 16; ++co) {
#pragma unroll
                for (int k = 0; k < 9; ++k)
                    acc[co] += w3[(co * 16 + ci) * 9 + k] * v[k];
            }
        }
        const int gy = y0 + oy, gx = x0 + ox;
#pragma unroll
        for (int co = 0; co < 16; ++co) {
            float r = acc[co] > 0.f ? acc[co] : 0.f;
            out[(((size_t)b * 16 + co) * HH + gy) * WW + gx] = r;
        }
    }
}

extern "C" void kernel_launch(void* const* d_in, const int* in_sizes, int n_in,
                              void* d_out, int out_size, void* d_ws, size_t ws_size,
                              hipStream_t stream) {
    const float* x  = (const float*)d_in[0];
    const float* w1 = (const float*)d_in[1];
    const float* w2 = (const float*)d_in[2];
    const float* w3 = (const float*)d_in[3];
    float* out = (float*)d_out;
    dim3 grid(BB * NT * NT);  // 9216 blocks
    dim3 block(512);
    fused_conv3<<<grid, block, 0, stream>>>(x, w1, w2, w3, out);
}